// Round 3
// baseline (382.524 us; speedup 1.0000x reference)
//
#include <hip/hip_runtime.h>
#include <hip/hip_bf16.h>

// ---------------------------------------------------------------------------
// GCN (3x GCNConv + relu) -> global mean pool -> MLP -> LayerNorm
// Strategy:
//   - Build CSR-by-destination each launch (fused histograms + scans + fill).
//   - deg includes self loop; dinv = rsqrt(deg); edge_norm = dinv[r]*dinv[c].
//   - Per layer: mm (h = x @ W, fp32, LDS-tiled, 8x4 register tile) then
//     wave-per-node aggregation (self term + in-edges), + bias + relu.
//     No fp32 atomics anywhere.
//   - Pool: batch is sorted -> per-graph ranges via 1-block scan; wave/graph.
//   - MLP + LayerNorm fused in one block-per-graph kernel.
// 14 dispatches total (1 memset + 13 kernels).
// ---------------------------------------------------------------------------

#define WAVE 64

// ---------------- histograms (edges + batch fused) ----------------

__global__ void hist_kernel(const int* __restrict__ cols, int* __restrict__ counts, int E,
                            const int* __restrict__ batch, int* __restrict__ gcnt, int n) {
    int idx = blockIdx.x * 256 + threadIdx.x;
    if (idx < E) {
        atomicAdd(&counts[cols[idx]], 1);
    } else {
        int i = idx - E;
        if (i < n) atomicAdd(&gcnt[batch[i]], 1);
    }
}

// ---------------- scans ----------------

__global__ void scan1_kernel(const int* __restrict__ counts, int* __restrict__ offs,
                             int* __restrict__ bsum, int n) {
    __shared__ int tmp[1024];
    int i = blockIdx.x * 1024 + threadIdx.x;
    int v = (i < n) ? counts[i] : 0;
    tmp[threadIdx.x] = v;
    __syncthreads();
    for (int o = 1; o < 1024; o <<= 1) {
        int x = (threadIdx.x >= o) ? tmp[threadIdx.x - o] : 0;
        __syncthreads();
        tmp[threadIdx.x] += x;
        __syncthreads();
    }
    if (i < n) offs[i] = tmp[threadIdx.x] - v;   // exclusive (within block)
    if (threadIdx.x == 1023) bsum[blockIdx.x] = tmp[1023];
}

// scans BOTH the per-block sums (bsum, nb entries) and the per-graph counts
// (gcnt -> goff, ng entries) in one block. nb, ng <= 1024.
__global__ void scan_meta_kernel(int* __restrict__ bsum, int nb,
                                 const int* __restrict__ gcnt, int* __restrict__ goff,
                                 int ng, int n_nodes) {
    __shared__ int ta[1024];
    __shared__ int tb[1024];
    int t = threadIdx.x;
    int va = (t < nb) ? bsum[t] : 0;
    int vb = (t < ng) ? gcnt[t] : 0;
    ta[t] = va;
    tb[t] = vb;
    __syncthreads();
    for (int o = 1; o < 1024; o <<= 1) {
        int xa = (t >= o) ? ta[t - o] : 0;
        int xb = (t >= o) ? tb[t - o] : 0;
        __syncthreads();
        ta[t] += xa;
        tb[t] += xb;
        __syncthreads();
    }
    if (t < nb) bsum[t] = ta[t] - va;   // exclusive block offsets
    if (t < ng) goff[t] = tb[t] - vb;   // exclusive graph offsets
    if (t == 0) goff[ng] = n_nodes;
}

__global__ void scan3_kernel(int* __restrict__ offs, const int* __restrict__ bsum,
                             const int* __restrict__ counts, float* __restrict__ dinv,
                             int n, int E) {
    int i = blockIdx.x * 256 + threadIdx.x;
    if (i < n) {
        offs[i] += bsum[i >> 10];
        dinv[i] = rsqrtf((float)(counts[i] + 1));  // +1 self loop; always > 0
    }
    if (i == 0) offs[n] = E;
}

__global__ void fill_kernel(const int* __restrict__ rows, const int* __restrict__ cols,
                            const int* __restrict__ offs, int* __restrict__ cursor,
                            const float* __restrict__ dinv,
                            int* __restrict__ esrc, float* __restrict__ enorm, int E) {
    int e = blockIdx.x * 256 + threadIdx.x;
    if (e >= E) return;
    int r = rows[e], c = cols[e];
    int pos = offs[c] + atomicAdd(&cursor[c], 1);
    esrc[pos]  = r;
    enorm[pos] = dinv[r] * dinv[c];
}

// ---------------- simple mm (layer 1, K=37) ----------------

template <int K, int F>
__global__ void mm_kernel(const float* __restrict__ X, const float* __restrict__ W,
                          float* __restrict__ out, int n) {
    constexpr int ROWS = 32;
    constexpr int CG = F / 4;
    __shared__ __align__(16) float Ws[K * F];
    __shared__ __align__(16) float xs[ROWS * K];
    int r0 = blockIdx.x * ROWS;
    for (int i = threadIdx.x; i < K * F; i += 256) Ws[i] = W[i];
    int nrow = n - r0; if (nrow > ROWS) nrow = ROWS;
    const float* Xb = X + (size_t)r0 * K;
    int tot = nrow * K;
    for (int i = threadIdx.x; i < tot; i += 256) xs[i] = Xb[i];
    __syncthreads();
    for (int idx = threadIdx.x; idx < ROWS * CG; idx += 256) {
        int r = idx / CG, cg = idx % CG;
        if (r >= nrow) break;
        float4 acc = {0.f, 0.f, 0.f, 0.f};
#pragma unroll
        for (int k = 0; k < K; ++k) {
            float xv = xs[r * K + k];
            float4 wv = *reinterpret_cast<const float4*>(&Ws[k * F + cg * 4]);
            acc.x += xv * wv.x; acc.y += xv * wv.y;
            acc.z += xv * wv.z; acc.w += xv * wv.w;
        }
        *reinterpret_cast<float4*>(&out[(size_t)(r0 + r) * F + cg * 4]) = acc;
    }
}

// ---------------- tiled mm (layers 2/3): 8 rows x 4 cols per thread ----------
// out[n,F] = X[n,K] @ W[K,F].  K % KC == 0, KC % 4 == 0.
// Per 4-k step per thread: 8 x-b128 + 4 W-b128 LDS reads feed 128 FMAs
// (~64% FMA efficiency vs ~31% for the naive version).
// xs row stride padded +4 floats so the 4 tr-groups of a wave hit distinct
// bank quads (conflict-free ds_read_b128); W row reads broadcast across tc.

template <int K, int F, int BR, int KC>
__global__ __launch_bounds__(256)
void mm_tiled_kernel(const float* __restrict__ X, const float* __restrict__ W,
                     float* __restrict__ out, int n) {
    constexpr int TC = F / 4;        // threads spanning columns (16 or 32)
    constexpr int TR = 256 / TC;     // threads spanning rows (16 or 8)
    constexpr int R  = BR / TR;      // rows per thread (8)
    constexpr int XS = KC + 4;       // padded LDS row stride (floats)
    static_assert(R == 8, "tile math assumes 8 rows/thread");
    static_assert(K % KC == 0 && KC % 4 == 0, "bad K chunking");

    __shared__ __align__(16) float Ws[K * F];
    __shared__ __align__(16) float xs[BR * XS];

    const int t  = threadIdx.x;
    const int tc = t % TC;
    const int tr = t / TC;
    const int r0 = blockIdx.x * BR;

    for (int i = t * 4; i < K * F; i += 1024)
        *reinterpret_cast<float4*>(&Ws[i]) = *reinterpret_cast<const float4*>(&W[i]);

    float4 acc[R];
#pragma unroll
    for (int i = 0; i < R; ++i) acc[i] = float4{0.f, 0.f, 0.f, 0.f};

    for (int kc = 0; kc < K; kc += KC) {
        __syncthreads();                       // xs reuse + (iter 0) Ws fence
        constexpr int VPR = KC / 4;            // float4 per xs row
        for (int idx = t; idx < BR * VPR; idx += 256) {
            int row = idx / VPR, col = idx % VPR;
            int gr = r0 + row; if (gr >= n) gr = n - 1;   // clamp, stay in-bounds
            *reinterpret_cast<float4*>(&xs[row * XS + col * 4]) =
                *reinterpret_cast<const float4*>(&X[(size_t)gr * K + kc + col * 4]);
        }
        __syncthreads();

#pragma unroll 2
        for (int kk = 0; kk < KC; kk += 4) {
            float4 xv[R];
#pragma unroll
            for (int i = 0; i < R; ++i)
                xv[i] = *reinterpret_cast<const float4*>(&xs[(tr + TR * i) * XS + kk]);
            float4 wv[4];
#pragma unroll
            for (int j = 0; j < 4; ++j)
                wv[j] = *reinterpret_cast<const float4*>(&Ws[(kc + kk + j) * F + tc * 4]);
#pragma unroll
            for (int i = 0; i < R; ++i) {
                const float* xp = reinterpret_cast<const float*>(&xv[i]);
#pragma unroll
                for (int j = 0; j < 4; ++j) {
                    float s = xp[j];
                    acc[i].x += s * wv[j].x;
                    acc[i].y += s * wv[j].y;
                    acc[i].z += s * wv[j].z;
                    acc[i].w += s * wv[j].w;
                }
            }
        }
    }

#pragma unroll
    for (int i = 0; i < R; ++i) {
        int gr = r0 + tr + TR * i;
        if (gr < n)
            *reinterpret_cast<float4*>(&out[(size_t)gr * F + tc * 4]) = acc[i];
    }
}

// ---------------- aggregation: out_i = relu(b + sum_j norm_ij * h_j) ----------------

template <int F>
__global__ void agg_kernel(const float* __restrict__ h, const int* __restrict__ offs,
                           const int* __restrict__ esrc, const float* __restrict__ enorm,
                           const float* __restrict__ dinv, const float* __restrict__ bias,
                           float* __restrict__ out, int n) {
    constexpr int J = F / WAVE;
    int wid  = threadIdx.x >> 6;
    int lane = threadIdx.x & 63;
    int node = blockIdx.x * 4 + wid;
    if (node >= n) return;
    float dv = dinv[node];
    float sn = dv * dv;
    float acc0[J], acc1[J];
#pragma unroll
    for (int j = 0; j < J; ++j) {
        acc0[j] = sn * h[(size_t)node * F + lane + 64 * j];
        acc1[j] = 0.f;
    }
    int s = offs[node], e = offs[node + 1];
    int k = s;
    for (; k + 1 < e; k += 2) {              // 2 gathers in flight per wave
        int   s0 = esrc[k],  s1 = esrc[k + 1];
        float w0 = enorm[k], w1 = enorm[k + 1];
#pragma unroll
        for (int j = 0; j < J; ++j) {
            acc0[j] += w0 * h[(size_t)s0 * F + lane + 64 * j];
            acc1[j] += w1 * h[(size_t)s1 * F + lane + 64 * j];
        }
    }
    if (k < e) {
        int   s0 = esrc[k];
        float w0 = enorm[k];
#pragma unroll
        for (int j = 0; j < J; ++j)
            acc0[j] += w0 * h[(size_t)s0 * F + lane + 64 * j];
    }
#pragma unroll
    for (int j = 0; j < J; ++j) {
        float v = acc0[j] + acc1[j] + bias[lane + 64 * j];
        out[(size_t)node * F + lane + 64 * j] = v > 0.f ? v : 0.f;
    }
}

// ---------------- graph pooling ----------------

__global__ void gpool_kernel(const float* __restrict__ h, const int* __restrict__ goff,
                             float* __restrict__ gmean, int ng) {
    int wid = threadIdx.x >> 6, lane = threadIdx.x & 63;
    int g = blockIdx.x * 4 + wid;
    if (g >= ng) return;
    int s = goff[g], e = goff[g + 1];
    float acc = 0.f;
    for (int i = s; i < e; ++i) acc += h[(size_t)i * 64 + lane];
    float c = (float)(e - s);
    gmean[g * 64 + lane] = acc / fmaxf(c, 1.0f);
}

// ---------------- MLP + LayerNorm ----------------

__global__ void mlp_kernel(const float* __restrict__ gmean,
                           const float* __restrict__ Wf1, const float* __restrict__ bf1,
                           const float* __restrict__ Wf2, const float* __restrict__ bf2,
                           const float* __restrict__ gamma, const float* __restrict__ beta,
                           float* __restrict__ out) {
    __shared__ float gs[64];
    __shared__ float ts[128];
    int g = blockIdx.x, t = threadIdx.x;
    if (t < 64) gs[t] = gmean[g * 64 + t];
    __syncthreads();
    float acc = bf1[t];
    for (int k = 0; k < 64; ++k) acc += gs[k] * Wf1[k * 128 + t];
    ts[t] = fmaxf(acc, 0.f);
    __syncthreads();
    if (t < 64) {
        float acc2 = bf2[t];
        for (int k = 0; k < 128; ++k) acc2 += ts[k] * Wf2[k * 64 + t];
        float u = fmaxf(acc2, 0.f);
        float mu = u;
        for (int o = 1; o < 64; o <<= 1) mu += __shfl_xor(mu, o);
        mu *= (1.0f / 64.0f);
        float d = u - mu;
        float var = d * d;
        for (int o = 1; o < 64; o <<= 1) var += __shfl_xor(var, o);
        var *= (1.0f / 64.0f);
        out[g * 64 + t] = d * rsqrtf(var + 1e-5f) * gamma[t] + beta[t];
    }
}

// ---------------- launch ----------------

extern "C" void kernel_launch(void* const* d_in, const int* in_sizes, int n_in,
                              void* d_out, int out_size, void* d_ws, size_t ws_size,
                              hipStream_t stream) {
    const float* x     = (const float*)d_in[0];
    const int*   eidx  = (const int*)d_in[1];
    const int*   batch = (const int*)d_in[2];
    const float* W1 = (const float*)d_in[3];  const float* b1 = (const float*)d_in[4];
    const float* W2 = (const float*)d_in[5];  const float* b2 = (const float*)d_in[6];
    const float* W3 = (const float*)d_in[7];  const float* b3 = (const float*)d_in[8];
    const float* Wf1 = (const float*)d_in[9];  const float* bf1 = (const float*)d_in[10];
    const float* Wf2 = (const float*)d_in[11]; const float* bf2 = (const float*)d_in[12];
    const float* gamma = (const float*)d_in[13]; const float* beta = (const float*)d_in[14];
    float* out = (float*)d_out;

    const int n  = in_sizes[2];          // 50000
    const int E  = in_sizes[1] / 2;      // 600000
    const int ng = out_size / 64;        // 1000
    const int NB = (n + 1023) / 1024;    // scan blocks (49)

    const int* rows = eidx;              // edge_index[0] (sources)
    const int* cols = eidx + E;          // edge_index[1] (targets)

    // -------- workspace carve (zeroed region first, single memset) --------
    size_t off = 0;
    auto carve = [&](size_t bytes) {
        void* p = (char*)d_ws + off;
        off += (bytes + 511) & ~(size_t)511;
        return p;
    };
    int*   counts = (int*)  carve((size_t)n * 4);        // | zeroed
    int*   cursor = (int*)  carve((size_t)n * 4);        // | zeroed
    int*   gcnt   = (int*)  carve((size_t)(ng + 1) * 4); // | zeroed
    size_t zbytes = off;
    int*   offs   = (int*)  carve((size_t)(n + 1) * 4);
    int*   bsum   = (int*)  carve((size_t)(NB + 1) * 4);
    float* dinv   = (float*)carve((size_t)n * 4);
    int*   esrc   = (int*)  carve((size_t)E * 4);
    float* enorm  = (float*)carve((size_t)E * 4);
    float* bufA   = (float*)carve((size_t)n * 128 * 4);
    float* bufB   = (float*)carve((size_t)n * 128 * 4);
    int*   goff   = (int*)  carve((size_t)(ng + 1) * 4);
    float* gmean  = (float*)carve((size_t)ng * 64 * 4);
    (void)ws_size;

    hipMemsetAsync(d_ws, 0, zbytes, stream);

    // -------- CSR build + graph ranges --------
    int gH = (E + n + 255) / 256;
    hist_kernel<<<gH, 256, 0, stream>>>(cols, counts, E, batch, gcnt, n);
    scan1_kernel<<<NB, 1024, 0, stream>>>(counts, offs, bsum, n);
    scan_meta_kernel<<<1, 1024, 0, stream>>>(bsum, NB, gcnt, goff, ng, n);
    scan3_kernel<<<(n + 255) / 256, 256, 0, stream>>>(offs, bsum, counts, dinv, n, E);
    fill_kernel<<<(E + 255) / 256, 256, 0, stream>>>(rows, cols, offs, cursor, dinv,
                                                     esrc, enorm, E);

    // -------- layers --------
    int gagg = (n + 3) / 4;
    mm_kernel<37, 64><<<(n + 31) / 32, 256, 0, stream>>>(x, W1, bufA, n);
    agg_kernel<64><<<gagg, 256, 0, stream>>>(bufA, offs, esrc, enorm, dinv, b1, bufB, n);
    // mm2: K=64, F=128, BR=64, KC=64  (LDS 32KB W + ~17KB xs)
    mm_tiled_kernel<64, 128, 64, 64><<<(n + 63) / 64, 256, 0, stream>>>(bufB, W2, bufA, n);
    agg_kernel<128><<<gagg, 256, 0, stream>>>(bufA, offs, esrc, enorm, dinv, b2, bufB, n);
    // mm3: K=128, F=64, BR=128, KC=64 (LDS 32KB W + ~34KB xs)
    mm_tiled_kernel<128, 64, 128, 64><<<(n + 127) / 128, 256, 0, stream>>>(bufB, W3, bufA, n);
    agg_kernel<64><<<gagg, 256, 0, stream>>>(bufA, offs, esrc, enorm, dinv, b3, bufB, n);

    // -------- pool + MLP + LayerNorm --------
    gpool_kernel<<<(ng + 3) / 4, 256, 0, stream>>>(bufB, goff, gmean, ng);
    mlp_kernel<<<ng, 128, 0, stream>>>(gmean, Wf1, bf1, Wf2, bf2, gamma, beta, out);
}

// Round 8
// 342.991 us; speedup vs baseline: 1.1153x; 1.1153x over previous
//
#include <hip/hip_runtime.h>
#include <hip/hip_bf16.h>

// ---------------------------------------------------------------------------
// GCN (3x GCNConv + relu) -> global mean pool -> MLP -> LayerNorm
//
// Key algebra:
//   A_n = D^-1/2 (A+I) D^-1/2 is separable: (A_n h)_i = dinv_i * S(dinv .* h)_i
//   where S = plain adjacency sum (incl self). So producers pre-scale rows by
//   dinv, agg does an UNWEIGHTED CSR sum, epilogue scales by dinv_i. No enorm.
//   Also agg commutes with the dense W: aggregate in the SMALLER feature dim:
//     L1: agg(x)[37] @ W1      L2: agg(h1)[64] @ W2      L3: agg(h2@W3)[64]
//
// Pipeline (14 dispatches):
//   memset | hist | scan1 | scan_meta | scan3(dinv) | scale(g0=x.*dinv) |
//   fill(esrc) | agg37 | mm1(+b1,relu,*dinv) | agg64 | mm2(+b2,relu) |
//   mm3(*dinv) | agg64(+b3,relu) | pool+mlp+layernorm
// ---------------------------------------------------------------------------

#define WAVE 64

// ---------------- histograms (edges + batch fused) ----------------

__global__ __launch_bounds__(256)
void hist_kernel(const int* __restrict__ cols, int* __restrict__ counts, int E,
                 const int* __restrict__ batch, int* __restrict__ gcnt, int n) {
    int idx = blockIdx.x * 256 + threadIdx.x;
    if (idx < E) {
        atomicAdd(&counts[cols[idx]], 1);
    } else {
        int i = idx - E;
        if (i < n) atomicAdd(&gcnt[batch[i]], 1);
    }
}

// ---------------- scans ----------------

__global__ __launch_bounds__(1024)
void scan1_kernel(const int* __restrict__ counts, int* __restrict__ offs,
                  int* __restrict__ bsum, int n) {
    __shared__ int tmp[1024];
    int i = blockIdx.x * 1024 + threadIdx.x;
    int v = (i < n) ? counts[i] : 0;
    tmp[threadIdx.x] = v;
    __syncthreads();
    for (int o = 1; o < 1024; o <<= 1) {
        int x = (threadIdx.x >= o) ? tmp[threadIdx.x - o] : 0;
        __syncthreads();
        tmp[threadIdx.x] += x;
        __syncthreads();
    }
    if (i < n) offs[i] = tmp[threadIdx.x] - v;   // exclusive (within block)
    if (threadIdx.x == 1023) bsum[blockIdx.x] = tmp[1023];
}

// scan bsum (nb) AND gcnt->goff (ng) in one block. nb, ng <= 1024.
__global__ __launch_bounds__(1024)
void scan_meta_kernel(int* __restrict__ bsum, int nb,
                      const int* __restrict__ gcnt, int* __restrict__ goff,
                      int ng, int n_nodes) {
    __shared__ int ta[1024];
    __shared__ int tb[1024];
    int t = threadIdx.x;
    int va = (t < nb) ? bsum[t] : 0;
    int vb = (t < ng) ? gcnt[t] : 0;
    ta[t] = va;
    tb[t] = vb;
    __syncthreads();
    for (int o = 1; o < 1024; o <<= 1) {
        int xa = (t >= o) ? ta[t - o] : 0;
        int xb = (t >= o) ? tb[t - o] : 0;
        __syncthreads();
        ta[t] += xa;
        tb[t] += xb;
        __syncthreads();
    }
    if (t < nb) bsum[t] = ta[t] - va;
    if (t < ng) goff[t] = tb[t] - vb;
    if (t == 0) goff[ng] = n_nodes;
}

__global__ __launch_bounds__(256)
void scan3_kernel(int* __restrict__ offs, const int* __restrict__ bsum,
                  const int* __restrict__ counts, float* __restrict__ dinv,
                  int n, int E) {
    int i = blockIdx.x * 256 + threadIdx.x;
    if (i < n) {
        offs[i] += bsum[i >> 10];
        dinv[i] = rsqrtf((float)(counts[i] + 1));  // +1 self loop; always > 0
    }
    if (i == 0) offs[n] = E;
}

__global__ __launch_bounds__(256)
void fill_kernel(const int* __restrict__ rows, const int* __restrict__ cols,
                 const int* __restrict__ offs, int* __restrict__ cursor,
                 int* __restrict__ esrc, int E) {
    int e = blockIdx.x * 256 + threadIdx.x;
    if (e >= E) return;
    int r = rows[e], c = cols[e];
    int pos = offs[c] + atomicAdd(&cursor[c], 1);
    esrc[pos] = r;
}

// ---------------- row pre-scale: g0 = x .* dinv[row] ----------------

template <int F>
__global__ __launch_bounds__(256)
void scale_kernel(const float* __restrict__ x, const float* __restrict__ dinv,
                  float* __restrict__ g0, int total) {
    int i = blockIdx.x * 256 + threadIdx.x;
    if (i < total) g0[i] = x[i] * dinv[i / F];
}

// ---------------- aggregation: out_i = post(dinv_i * sum_{j in N(i)+i} g_j) ----

template <int F>
__global__ __launch_bounds__(256)
void agg_kernel(const float* __restrict__ g, const int* __restrict__ offs,
                const int* __restrict__ esrc, const float* __restrict__ dinv,
                const float* __restrict__ bias, int do_relu,
                float* __restrict__ out, int n) {
    constexpr int J = (F + 63) / 64;
    int wid  = threadIdx.x >> 6;
    int lane = threadIdx.x & 63;
    int node = blockIdx.x * 4 + wid;
    if (node >= n) return;
    float acc0[J], acc1[J], acc2[J], acc3[J];
#pragma unroll
    for (int j = 0; j < J; ++j) {
        int c = lane + 64 * j; if (F % 64 && c >= F) c = F - 1;   // clamped dup
        acc0[j] = g[(size_t)node * F + c];                        // self term
        acc1[j] = 0.f; acc2[j] = 0.f; acc3[j] = 0.f;
    }
    int s = offs[node], e = offs[node + 1];
    int k = s;
    for (; k + 3 < e; k += 4) {                    // 4 gathers in flight / wave
        int s0 = esrc[k], s1 = esrc[k + 1], s2 = esrc[k + 2], s3 = esrc[k + 3];
#pragma unroll
        for (int j = 0; j < J; ++j) {
            int c = lane + 64 * j; if (F % 64 && c >= F) c = F - 1;
            acc0[j] += g[(size_t)s0 * F + c];
            acc1[j] += g[(size_t)s1 * F + c];
            acc2[j] += g[(size_t)s2 * F + c];
            acc3[j] += g[(size_t)s3 * F + c];
        }
    }
    for (; k < e; ++k) {
        int s0 = esrc[k];
#pragma unroll
        for (int j = 0; j < J; ++j) {
            int c = lane + 64 * j; if (F % 64 && c >= F) c = F - 1;
            acc0[j] += g[(size_t)s0 * F + c];
        }
    }
    float dv = dinv[node];
#pragma unroll
    for (int j = 0; j < J; ++j) {
        int c = lane + 64 * j;
        if (F % 64 == 0 || c < F) {
            float v = ((acc0[j] + acc1[j]) + (acc2[j] + acc3[j])) * dv;
            if (bias)    v += bias[c];
            if (do_relu) v = fmaxf(v, 0.f);
            out[(size_t)node * F + c] = v;
        }
    }
}

// ---------------- simple mm (layer 1, K=37) + fused epilogue ----------------
// out[r,c] = post(sum_k X[r,k] W[k,c]); post: +bias, relu, *dscale[r]

template <int K, int F>
__global__ __launch_bounds__(256)
void mm_kernel(const float* __restrict__ X, const float* __restrict__ W,
               const float* __restrict__ bias, const float* __restrict__ dscale,
               int do_relu, float* __restrict__ out, int n) {
    constexpr int ROWS = 32;
    constexpr int CG = F / 4;
    __shared__ __align__(16) float Ws[K * F];
    __shared__ __align__(16) float xs[ROWS * K];
    int r0 = blockIdx.x * ROWS;
    for (int i = threadIdx.x; i < K * F; i += 256) Ws[i] = W[i];
    int nrow = n - r0; if (nrow > ROWS) nrow = ROWS;
    const float* Xb = X + (size_t)r0 * K;
    int tot = nrow * K;
    for (int i = threadIdx.x; i < tot; i += 256) xs[i] = Xb[i];
    __syncthreads();
    for (int idx = threadIdx.x; idx < ROWS * CG; idx += 256) {
        int r = idx / CG, cg = idx % CG;
        if (r >= nrow) break;
        float4 acc = {0.f, 0.f, 0.f, 0.f};
#pragma unroll
        for (int k = 0; k < K; ++k) {
            float xv = xs[r * K + k];
            float4 wv = *reinterpret_cast<const float4*>(&Ws[k * F + cg * 4]);
            acc.x += xv * wv.x; acc.y += xv * wv.y;
            acc.z += xv * wv.z; acc.w += xv * wv.w;
        }
        if (bias) {
            const float4 bv = *reinterpret_cast<const float4*>(&bias[cg * 4]);
            acc.x += bv.x; acc.y += bv.y; acc.z += bv.z; acc.w += bv.w;
        }
        if (do_relu) {
            acc.x = fmaxf(acc.x, 0.f); acc.y = fmaxf(acc.y, 0.f);
            acc.z = fmaxf(acc.z, 0.f); acc.w = fmaxf(acc.w, 0.f);
        }
        if (dscale) {
            float dv = dscale[r0 + r];
            acc.x *= dv; acc.y *= dv; acc.z *= dv; acc.w *= dv;
        }
        *reinterpret_cast<float4*>(&out[(size_t)(r0 + r) * F + cg * 4]) = acc;
    }
}

// ---------------- tiled mm (layers 2/3): 8 rows x 4 cols per thread ----------

template <int K, int F, int BR, int KC>
__global__ __launch_bounds__(256)
void mm_tiled_kernel(const float* __restrict__ X, const float* __restrict__ W,
                     const float* __restrict__ bias, const float* __restrict__ dscale,
                     int do_relu, float* __restrict__ out, int n) {
    constexpr int TC = F / 4;        // threads spanning columns
    constexpr int TR = 256 / TC;     // threads spanning rows
    constexpr int R  = BR / TR;      // rows per thread (8)
    constexpr int XS = KC + 4;       // padded LDS row stride
    static_assert(R == 8, "tile math assumes 8 rows/thread");
    static_assert(K % KC == 0 && KC % 4 == 0, "bad K chunking");

    __shared__ __align__(16) float Ws[K * F];
    __shared__ __align__(16) float xs[BR * XS];

    const int t  = threadIdx.x;
    const int tc = t % TC;
    const int tr = t / TC;
    const int r0 = blockIdx.x * BR;

    for (int i = t * 4; i < K * F; i += 1024)
        *reinterpret_cast<float4*>(&Ws[i]) = *reinterpret_cast<const float4*>(&W[i]);

    float4 acc[R];
#pragma unroll
    for (int i = 0; i < R; ++i) acc[i] = float4{0.f, 0.f, 0.f, 0.f};

    for (int kc = 0; kc < K; kc += KC) {
        __syncthreads();
        constexpr int VPR = KC / 4;
        for (int idx = t; idx < BR * VPR; idx += 256) {
            int row = idx / VPR, col = idx % VPR;
            int gr = r0 + row; if (gr >= n) gr = n - 1;
            *reinterpret_cast<float4*>(&xs[row * XS + col * 4]) =
                *reinterpret_cast<const float4*>(&X[(size_t)gr * K + kc + col * 4]);
        }
        __syncthreads();

#pragma unroll 2
        for (int kk = 0; kk < KC; kk += 4) {
            float4 xv[R];
#pragma unroll
            for (int i = 0; i < R; ++i)
                xv[i] = *reinterpret_cast<const float4*>(&xs[(tr + TR * i) * XS + kk]);
            float4 wv[4];
#pragma unroll
            for (int j = 0; j < 4; ++j)
                wv[j] = *reinterpret_cast<const float4*>(&Ws[(kc + kk + j) * F + tc * 4]);
#pragma unroll
            for (int i = 0; i < R; ++i) {
                const float* xp = reinterpret_cast<const float*>(&xv[i]);
#pragma unroll
                for (int j = 0; j < 4; ++j) {
                    float s = xp[j];
                    acc[i].x += s * wv[j].x;
                    acc[i].y += s * wv[j].y;
                    acc[i].z += s * wv[j].z;
                    acc[i].w += s * wv[j].w;
                }
            }
        }
    }

    float4 bv = {0.f, 0.f, 0.f, 0.f};
    if (bias) bv = *reinterpret_cast<const float4*>(&bias[tc * 4]);
#pragma unroll
    for (int i = 0; i < R; ++i) {
        int gr = r0 + tr + TR * i;
        if (gr < n) {
            float4 v = acc[i];
            if (bias) { v.x += bv.x; v.y += bv.y; v.z += bv.z; v.w += bv.w; }
            if (do_relu) {
                v.x = fmaxf(v.x, 0.f); v.y = fmaxf(v.y, 0.f);
                v.z = fmaxf(v.z, 0.f); v.w = fmaxf(v.w, 0.f);
            }
            if (dscale) {
                float dv = dscale[gr];
                v.x *= dv; v.y *= dv; v.z *= dv; v.w *= dv;
            }
            *reinterpret_cast<float4*>(&out[(size_t)gr * F + tc * 4]) = v;
        }
    }
}

// ---------------- pool + MLP + LayerNorm (one block / graph, 128 thr) --------

__global__ __launch_bounds__(128)
void poolmlp_kernel(const float* __restrict__ h, const int* __restrict__ goff,
                    const float* __restrict__ Wf1, const float* __restrict__ bf1,
                    const float* __restrict__ Wf2, const float* __restrict__ bf2,
                    const float* __restrict__ gamma, const float* __restrict__ beta,
                    float* __restrict__ out) {
    __shared__ float red[128];
    __shared__ float gs[64];
    __shared__ float ts[128];
    int g = blockIdx.x, t = threadIdx.x;
    int f = t & 63, half = t >> 6;
    int s = goff[g], e = goff[g + 1];
    float acc = 0.f;
    for (int i = s + half; i < e; i += 2) acc += h[(size_t)i * 64 + f];
    red[t] = acc;
    __syncthreads();
    if (t < 64) {
        float c = (float)(e - s);
        gs[t] = (red[t] + red[t + 64]) / fmaxf(c, 1.0f);
    }
    __syncthreads();
    float a1 = bf1[t];
    for (int k = 0; k < 64; ++k) a1 += gs[k] * Wf1[k * 128 + t];
    ts[t] = fmaxf(a1, 0.f);
    __syncthreads();
    if (t < 64) {
        float a2 = bf2[t];
        for (int k = 0; k < 128; ++k) a2 += ts[k] * Wf2[k * 64 + t];
        float u = fmaxf(a2, 0.f);
        float mu = u;
        for (int o = 1; o < 64; o <<= 1) mu += __shfl_xor(mu, o);
        mu *= (1.0f / 64.0f);
        float d = u - mu;
        float var = d * d;
        for (int o = 1; o < 64; o <<= 1) var += __shfl_xor(var, o);
        var *= (1.0f / 64.0f);
        out[g * 64 + t] = d * rsqrtf(var + 1e-5f) * gamma[t] + beta[t];
    }
}

// ---------------- launch ----------------

extern "C" void kernel_launch(void* const* d_in, const int* in_sizes, int n_in,
                              void* d_out, int out_size, void* d_ws, size_t ws_size,
                              hipStream_t stream) {
    const float* x     = (const float*)d_in[0];
    const int*   eidx  = (const int*)d_in[1];
    const int*   batch = (const int*)d_in[2];
    const float* W1 = (const float*)d_in[3];  const float* b1 = (const float*)d_in[4];
    const float* W2 = (const float*)d_in[5];  const float* b2 = (const float*)d_in[6];
    const float* W3 = (const float*)d_in[7];  const float* b3 = (const float*)d_in[8];
    const float* Wf1 = (const float*)d_in[9];  const float* bf1 = (const float*)d_in[10];
    const float* Wf2 = (const float*)d_in[11]; const float* bf2 = (const float*)d_in[12];
    const float* gamma = (const float*)d_in[13]; const float* beta = (const float*)d_in[14];
    float* out = (float*)d_out;

    const int n  = in_sizes[2];          // 50000
    const int E  = in_sizes[1] / 2;      // 600000
    const int ng = out_size / 64;        // 1000
    const int NB = (n + 1023) / 1024;    // scan blocks (49)

    const int* rows = eidx;              // edge_index[0] (sources)
    const int* cols = eidx + E;          // edge_index[1] (targets)

    // -------- workspace carve (zeroed region first, single memset) --------
    size_t off = 0;
    auto carve = [&](size_t bytes) {
        void* p = (char*)d_ws + off;
        off += (bytes + 511) & ~(size_t)511;
        return p;
    };
    int*   counts = (int*)  carve((size_t)n * 4);        // | zeroed
    int*   cursor = (int*)  carve((size_t)n * 4);        // | zeroed
    int*   gcnt   = (int*)  carve((size_t)(ng + 1) * 4); // | zeroed
    size_t zbytes = off;
    int*   offs   = (int*)  carve((size_t)(n + 1) * 4);
    int*   bsum   = (int*)  carve((size_t)(NB + 1) * 4);
    float* dinv   = (float*)carve((size_t)n * 4);
    int*   esrc   = (int*)  carve((size_t)E * 4);
    int*   goff   = (int*)  carve((size_t)(ng + 1) * 4);
    float* bufA   = (float*)carve((size_t)n * 128 * 4);  // g0 / h1' / h2 / h3
    float* bufB   = (float*)carve((size_t)n * 64 * 4);   // a0 / t1 / q
    (void)ws_size;

    hipMemsetAsync(d_ws, 0, zbytes, stream);

    // -------- CSR build + graph ranges + dinv --------
    int gH = (E + n + 255) / 256;
    hist_kernel<<<gH, 256, 0, stream>>>(cols, counts, E, batch, gcnt, n);
    scan1_kernel<<<NB, 1024, 0, stream>>>(counts, offs, bsum, n);
    scan_meta_kernel<<<1, 1024, 0, stream>>>(bsum, NB, gcnt, goff, ng, n);
    scan3_kernel<<<(n + 255) / 256, 256, 0, stream>>>(offs, bsum, counts, dinv, n, E);
    scale_kernel<37><<<(n * 37 + 255) / 256, 256, 0, stream>>>(x, dinv, bufA, n * 37);
    fill_kernel<<<(E + 255) / 256, 256, 0, stream>>>(rows, cols, offs, cursor, esrc, E);

    // -------- layers (agg in the smaller feature dim; scales fused) --------
    int gagg = (n + 3) / 4;
    // L1: a0 = dinv.*S(g0);  h1' = relu(a0@W1+b1).*dinv  (pre-scaled for L2)
    agg_kernel<37><<<gagg, 256, 0, stream>>>(bufA, offs, esrc, dinv, nullptr, 0, bufB, n);
    mm_kernel<37, 64><<<(n + 31) / 32, 256, 0, stream>>>(bufB, W1, b1, dinv, 1, bufA, n);
    // L2: t1 = dinv.*S(h1');  h2 = relu(t1@W2+b2)
    agg_kernel<64><<<gagg, 256, 0, stream>>>(bufA, offs, esrc, dinv, nullptr, 0, bufB, n);
    mm_tiled_kernel<64, 128, 64, 64><<<(n + 63) / 64, 256, 0, stream>>>(
        bufB, W2, b2, nullptr, 1, bufA, n);
    // L3: q = (h2@W3).*dinv;  h3 = relu(dinv.*S(q)+b3)
    mm_tiled_kernel<128, 64, 128, 64><<<(n + 127) / 128, 256, 0, stream>>>(
        bufA, W3, nullptr, dinv, 0, bufB, n);
    agg_kernel<64><<<gagg, 256, 0, stream>>>(bufB, offs, esrc, dinv, b3, 1, bufA, n);

    // -------- pool + MLP + LayerNorm --------
    poolmlp_kernel<<<ng, 128, 0, stream>>>(bufA, goff, Wf1, bf1, Wf2, bf2, gamma, beta, out);
}

// Round 9
// 332.422 us; speedup vs baseline: 1.1507x; 1.0318x over previous
//
#include <hip/hip_runtime.h>
#include <hip/hip_bf16.h>

// ---------------------------------------------------------------------------
// GCN (3x GCNConv + relu) -> global mean pool -> MLP -> LayerNorm
//
// Algebra:
//   A_n = D^-1/2 (A+I) D^-1/2 separable: (A_n h)_i = dinv_i * S(dinv .* h)_i.
//   Aggregate in the SMALLER feature dim (agg commutes with dense W):
//     L1: aggW(x)[37] @ W1   L2: agg(h1')[64] @ W2   L3: agg((h2@W3).*dinv)[64]
//   aggW applies dinv[src] per edge (x gathered directly, no scale pass).
//   h1' pre-scaled by dinv in mm1 epilogue; q pre-scaled in mm23 epilogue.
//
// Pipeline (12 dispatches):
//   memset | hist | scan1 | scan_meta | scan3(dinv) | fill(esrc) |
//   agg37(wsrc) | mm1(+b1,relu,*dinv) | agg64 | mm23(+b2,relu,@W3,*dinv) |
//   agg64(+b3,relu) | pool+mlp+layernorm
// ---------------------------------------------------------------------------

// ---------------- histograms (edges + batch fused) ----------------

__global__ __launch_bounds__(256)
void hist_kernel(const int* __restrict__ cols, int* __restrict__ counts, int E,
                 const int* __restrict__ batch, int* __restrict__ gcnt, int n) {
    int idx = blockIdx.x * 256 + threadIdx.x;
    if (idx < E) {
        atomicAdd(&counts[cols[idx]], 1);
    } else {
        int i = idx - E;
        if (i < n) atomicAdd(&gcnt[batch[i]], 1);
    }
}

// ---------------- scans ----------------

__global__ __launch_bounds__(1024)
void scan1_kernel(const int* __restrict__ counts, int* __restrict__ offs,
                  int* __restrict__ bsum, int n) {
    __shared__ int tmp[1024];
    int i = blockIdx.x * 1024 + threadIdx.x;
    int v = (i < n) ? counts[i] : 0;
    tmp[threadIdx.x] = v;
    __syncthreads();
    for (int o = 1; o < 1024; o <<= 1) {
        int x = (threadIdx.x >= o) ? tmp[threadIdx.x - o] : 0;
        __syncthreads();
        tmp[threadIdx.x] += x;
        __syncthreads();
    }
    if (i < n) offs[i] = tmp[threadIdx.x] - v;   // exclusive (within block)
    if (threadIdx.x == 1023) bsum[blockIdx.x] = tmp[1023];
}

// scan bsum (nb) AND gcnt->goff (ng) in one block. nb, ng <= 1024.
__global__ __launch_bounds__(1024)
void scan_meta_kernel(int* __restrict__ bsum, int nb,
                      const int* __restrict__ gcnt, int* __restrict__ goff,
                      int ng, int n_nodes) {
    __shared__ int ta[1024];
    __shared__ int tb[1024];
    int t = threadIdx.x;
    int va = (t < nb) ? bsum[t] : 0;
    int vb = (t < ng) ? gcnt[t] : 0;
    ta[t] = va;
    tb[t] = vb;
    __syncthreads();
    for (int o = 1; o < 1024; o <<= 1) {
        int xa = (t >= o) ? ta[t - o] : 0;
        int xb = (t >= o) ? tb[t - o] : 0;
        __syncthreads();
        ta[t] += xa;
        tb[t] += xb;
        __syncthreads();
    }
    if (t < nb) bsum[t] = ta[t] - va;
    if (t < ng) goff[t] = tb[t] - vb;
    if (t == 0) goff[ng] = n_nodes;
}

__global__ __launch_bounds__(256)
void scan3_kernel(int* __restrict__ offs, const int* __restrict__ bsum,
                  const int* __restrict__ counts, float* __restrict__ dinv,
                  int n, int E) {
    int i = blockIdx.x * 256 + threadIdx.x;
    if (i < n) {
        offs[i] += bsum[i >> 10];
        dinv[i] = rsqrtf((float)(counts[i] + 1));  // +1 self loop; always > 0
    }
    if (i == 0) offs[n] = E;
}

__global__ __launch_bounds__(256)
void fill_kernel(const int* __restrict__ rows, const int* __restrict__ cols,
                 const int* __restrict__ offs, int* __restrict__ cursor,
                 int* __restrict__ esrc, int E) {
    int e = blockIdx.x * 256 + threadIdx.x;
    if (e >= E) return;
    int r = rows[e], c = cols[e];
    int pos = offs[c] + atomicAdd(&cursor[c], 1);
    esrc[pos] = r;
}

// ---------------- aggregation (F<=64, wave per node, 8-deep gather ILP) ------
// out_i = post( dinv_i * [ wself*g_i + sum_{j in N(i)} w_j * g_j ] )
// WSRC=1: w = dinv[src] (first layer, g = raw x). WSRC=0: w = 1 (pre-scaled g).

template <int F, int WSRC>
__global__ __launch_bounds__(256)
void agg_kernel(const float* __restrict__ g, const int* __restrict__ offs,
                const int* __restrict__ esrc, const float* __restrict__ dinv,
                const float* __restrict__ bias, int do_relu,
                float* __restrict__ out, int n) {
    static_assert(F <= 64, "one lane per feature");
    int wid  = threadIdx.x >> 6;
    int lane = threadIdx.x & 63;
    int node = blockIdx.x * 4 + wid;
    if (node >= n) return;
    int c = (lane < F) ? lane : (F - 1);          // clamped dup read, write-guarded
    float dv = dinv[node];
    float a0 = (WSRC ? dv : 1.0f) * g[(size_t)node * F + c];   // self term
    float a1 = 0.f, a2 = 0.f, a3 = 0.f, a4 = 0.f, a5 = 0.f, a6 = 0.f, a7 = 0.f;
    int s = offs[node], e = offs[node + 1];
    int k = s;
    for (; k + 7 < e; k += 8) {                   // 8 gathers in flight / wave
        int s0 = esrc[k],     s1 = esrc[k + 1], s2 = esrc[k + 2], s3 = esrc[k + 3];
        int s4 = esrc[k + 4], s5 = esrc[k + 5], s6 = esrc[k + 6], s7 = esrc[k + 7];
        float w0 = WSRC ? dinv[s0] : 1.f, w1 = WSRC ? dinv[s1] : 1.f;
        float w2 = WSRC ? dinv[s2] : 1.f, w3 = WSRC ? dinv[s3] : 1.f;
        float w4 = WSRC ? dinv[s4] : 1.f, w5 = WSRC ? dinv[s5] : 1.f;
        float w6 = WSRC ? dinv[s6] : 1.f, w7 = WSRC ? dinv[s7] : 1.f;
        a0 += w0 * g[(size_t)s0 * F + c];
        a1 += w1 * g[(size_t)s1 * F + c];
        a2 += w2 * g[(size_t)s2 * F + c];
        a3 += w3 * g[(size_t)s3 * F + c];
        a4 += w4 * g[(size_t)s4 * F + c];
        a5 += w5 * g[(size_t)s5 * F + c];
        a6 += w6 * g[(size_t)s6 * F + c];
        a7 += w7 * g[(size_t)s7 * F + c];
    }
    for (; k < e; ++k) {
        int s0 = esrc[k];
        float w0 = WSRC ? dinv[s0] : 1.f;
        a0 += w0 * g[(size_t)s0 * F + c];
    }
    float v = (((a0 + a1) + (a2 + a3)) + ((a4 + a5) + (a6 + a7))) * dv;
    if (bias)    v += bias[c];
    if (do_relu) v = fmaxf(v, 0.f);
    if (lane < F) out[(size_t)node * F + c] = v;
}

// ---------------- mm1 (layer 1, K=37) + fused epilogue ----------------------
// out[r,c] = post(sum_k X[r,k] W[k,c]); post: +bias, relu, *dscale[r]

template <int K, int F>
__global__ __launch_bounds__(256)
void mm_kernel(const float* __restrict__ X, const float* __restrict__ W,
               const float* __restrict__ bias, const float* __restrict__ dscale,
               int do_relu, float* __restrict__ out, int n) {
    constexpr int ROWS = 32;
    constexpr int CG = F / 4;
    __shared__ __align__(16) float Ws[K * F];
    __shared__ __align__(16) float xs[ROWS * K];
    int r0 = blockIdx.x * ROWS;
    for (int i = threadIdx.x; i < K * F; i += 256) Ws[i] = W[i];
    int nrow = n - r0; if (nrow > ROWS) nrow = ROWS;
    const float* Xb = X + (size_t)r0 * K;
    int tot = nrow * K;
    for (int i = threadIdx.x; i < tot; i += 256) xs[i] = Xb[i];
    __syncthreads();
    for (int idx = threadIdx.x; idx < ROWS * CG; idx += 256) {
        int r = idx / CG, cg = idx % CG;
        if (r >= nrow) break;
        float4 acc = {0.f, 0.f, 0.f, 0.f};
#pragma unroll
        for (int k = 0; k < K; ++k) {
            float xv = xs[r * K + k];
            float4 wv = *reinterpret_cast<const float4*>(&Ws[k * F + cg * 4]);
            acc.x += xv * wv.x; acc.y += xv * wv.y;
            acc.z += xv * wv.z; acc.w += xv * wv.w;
        }
        if (bias) {
            const float4 bv = *reinterpret_cast<const float4*>(&bias[cg * 4]);
            acc.x += bv.x; acc.y += bv.y; acc.z += bv.z; acc.w += bv.w;
        }
        if (do_relu) {
            acc.x = fmaxf(acc.x, 0.f); acc.y = fmaxf(acc.y, 0.f);
            acc.z = fmaxf(acc.z, 0.f); acc.w = fmaxf(acc.w, 0.f);
        }
        if (dscale) {
            float dv = dscale[r0 + r];
            acc.x *= dv; acc.y *= dv; acc.z *= dv; acc.w *= dv;
        }
        *reinterpret_cast<float4*>(&out[(size_t)(r0 + r) * F + cg * 4]) = acc;
    }
}

// ---------------- fused mm2+mm3: q = (relu(t1@W2+b2))@W3 .* dinv -------------
// t1:[n,64], W2:[64,128], W3:[128,64], q:[n,64]. 32-row tile per block.
// Wbuf time-shares W2 then W3 (8192 floats); Xbuf time-shares the x-tile
// (stride 68) then the h2 tile (stride 130). LDS ~49 KB -> 3 blocks/CU.

__global__ __launch_bounds__(256)
void mm23_kernel(const float* __restrict__ X, const float* __restrict__ W2,
                 const float* __restrict__ b2, const float* __restrict__ W3,
                 const float* __restrict__ dinv, float* __restrict__ out, int n) {
    __shared__ __align__(16) float Wbuf[64 * 128];
    __shared__ __align__(16) float Xbuf[32 * 130];
    const int t  = threadIdx.x;
    const int r0 = blockIdx.x * 32;

    // phase 0: load W2 + x-tile
    for (int i = t * 4; i < 8192; i += 1024)
        *reinterpret_cast<float4*>(&Wbuf[i]) = *reinterpret_cast<const float4*>(&W2[i]);
    for (int idx = t; idx < 32 * 16; idx += 256) {
        int row = idx / 16, col = idx % 16;
        int gr = r0 + row; if (gr >= n) gr = n - 1;
        *reinterpret_cast<float4*>(&Xbuf[row * 68 + col * 4]) =
            *reinterpret_cast<const float4*>(&X[(size_t)gr * 64 + col * 4]);
    }
    __syncthreads();

    // phase 1: h2 = relu(x@W2+b2); thread (tc=t%32, tr=t/32): rows tr+8i, cols tc*4
    const int tc = t % 32, tr = t / 32;
    float4 h2[4];
#pragma unroll
    for (int i = 0; i < 4; ++i) h2[i] = float4{0.f, 0.f, 0.f, 0.f};
#pragma unroll 2
    for (int kk = 0; kk < 64; kk += 4) {
        float4 xv[4];
#pragma unroll
        for (int i = 0; i < 4; ++i)
            xv[i] = *reinterpret_cast<const float4*>(&Xbuf[(tr + 8 * i) * 68 + kk]);
        float4 wv[4];
#pragma unroll
        for (int j = 0; j < 4; ++j)
            wv[j] = *reinterpret_cast<const float4*>(&Wbuf[(kk + j) * 128 + tc * 4]);
#pragma unroll
        for (int i = 0; i < 4; ++i) {
            const float* xp = reinterpret_cast<const float*>(&xv[i]);
#pragma unroll
            for (int j = 0; j < 4; ++j) {
                float s = xp[j];
                h2[i].x += s * wv[j].x; h2[i].y += s * wv[j].y;
                h2[i].z += s * wv[j].z; h2[i].w += s * wv[j].w;
            }
        }
    }
    {
        const float4 bv = *reinterpret_cast<const float4*>(&b2[tc * 4]);
#pragma unroll
        for (int i = 0; i < 4; ++i) {
            h2[i].x = fmaxf(h2[i].x + bv.x, 0.f);
            h2[i].y = fmaxf(h2[i].y + bv.y, 0.f);
            h2[i].z = fmaxf(h2[i].z + bv.z, 0.f);
            h2[i].w = fmaxf(h2[i].w + bv.w, 0.f);
        }
    }
    __syncthreads();   // all reads of Wbuf/Xbuf done

    // phase 2: write h2 tile (stride 130); load W3 over W2
#pragma unroll
    for (int i = 0; i < 4; ++i)
        *reinterpret_cast<float4*>(&Xbuf[(tr + 8 * i) * 130 + tc * 4]) = h2[i];
    for (int i = t * 4; i < 8192; i += 1024)
        *reinterpret_cast<float4*>(&Wbuf[i]) = *reinterpret_cast<const float4*>(&W3[i]);
    __syncthreads();

    // phase 3: q = h2@W3; thread (tc3=t%16, tr3=t/16): rows {tr3, tr3+16}, cols tc3*4
    const int tc3 = t % 16, tr3 = t / 16;
    float4 q0 = {0.f, 0.f, 0.f, 0.f}, q1 = {0.f, 0.f, 0.f, 0.f};
#pragma unroll 2
    for (int k2 = 0; k2 < 128; k2 += 4) {
        float4 x0 = *reinterpret_cast<const float4*>(&Xbuf[tr3 * 130 + k2]);
        float4 x1 = *reinterpret_cast<const float4*>(&Xbuf[(tr3 + 16) * 130 + k2]);
        float4 wv[4];
#pragma unroll
        for (int j = 0; j < 4; ++j)
            wv[j] = *reinterpret_cast<const float4*>(&Wbuf[(k2 + j) * 64 + tc3 * 4]);
        const float* p0 = reinterpret_cast<const float*>(&x0);
        const float* p1 = reinterpret_cast<const float*>(&x1);
#pragma unroll
        for (int j = 0; j < 4; ++j) {
            float s0 = p0[j], s1 = p1[j];
            q0.x += s0 * wv[j].x; q0.y += s0 * wv[j].y;
            q0.z += s0 * wv[j].z; q0.w += s0 * wv[j].w;
            q1.x += s1 * wv[j].x; q1.y += s1 * wv[j].y;
            q1.z += s1 * wv[j].z; q1.w += s1 * wv[j].w;
        }
    }
    int gr0 = r0 + tr3, gr1 = r0 + tr3 + 16;
    if (gr0 < n) {
        float dv = dinv[gr0];
        q0.x *= dv; q0.y *= dv; q0.z *= dv; q0.w *= dv;
        *reinterpret_cast<float4*>(&out[(size_t)gr0 * 64 + tc3 * 4]) = q0;
    }
    if (gr1 < n) {
        float dv = dinv[gr1];
        q1.x *= dv; q1.y *= dv; q1.z *= dv; q1.w *= dv;
        *reinterpret_cast<float4*>(&out[(size_t)gr1 * 64 + tc3 * 4]) = q1;
    }
}

// ---------------- pool + MLP + LayerNorm (one block / graph, 128 thr) --------

__global__ __launch_bounds__(128)
void poolmlp_kernel(const float* __restrict__ h, const int* __restrict__ goff,
                    const float* __restrict__ Wf1, const float* __restrict__ bf1,
                    const float* __restrict__ Wf2, const float* __restrict__ bf2,
                    const float* __restrict__ gamma, const float* __restrict__ beta,
                    float* __restrict__ out) {
    __shared__ float red[128];
    __shared__ float gs[64];
    __shared__ float ts[128];
    int g = blockIdx.x, t = threadIdx.x;
    int f = t & 63, half = t >> 6;
    int s = goff[g], e = goff[g + 1];
    float acc = 0.f;
    for (int i = s + half; i < e; i += 2) acc += h[(size_t)i * 64 + f];
    red[t] = acc;
    __syncthreads();
    if (t < 64) {
        float c = (float)(e - s);
        gs[t] = (red[t] + red[t + 64]) / fmaxf(c, 1.0f);
    }
    __syncthreads();
    float a1 = bf1[t];
    for (int k = 0; k < 64; ++k) a1 += gs[k] * Wf1[k * 128 + t];
    ts[t] = fmaxf(a1, 0.f);
    __syncthreads();
    if (t < 64) {
        float a2 = bf2[t];
        for (int k = 0; k < 128; ++k) a2 += ts[k] * Wf2[k * 64 + t];
        float u = fmaxf(a2, 0.f);
        float mu = u;
        for (int o = 1; o < 64; o <<= 1) mu += __shfl_xor(mu, o);
        mu *= (1.0f / 64.0f);
        float d = u - mu;
        float var = d * d;
        for (int o = 1; o < 64; o <<= 1) var += __shfl_xor(var, o);
        var *= (1.0f / 64.0f);
        out[g * 64 + t] = d * rsqrtf(var + 1e-5f) * gamma[t] + beta[t];
    }
}

// ---------------- launch ----------------

extern "C" void kernel_launch(void* const* d_in, const int* in_sizes, int n_in,
                              void* d_out, int out_size, void* d_ws, size_t ws_size,
                              hipStream_t stream) {
    const float* x     = (const float*)d_in[0];
    const int*   eidx  = (const int*)d_in[1];
    const int*   batch = (const int*)d_in[2];
    const float* W1 = (const float*)d_in[3];  const float* b1 = (const float*)d_in[4];
    const float* W2 = (const float*)d_in[5];  const float* b2 = (const float*)d_in[6];
    const float* W3 = (const float*)d_in[7];  const float* b3 = (const float*)d_in[8];
    const float* Wf1 = (const float*)d_in[9];  const float* bf1 = (const float*)d_in[10];
    const float* Wf2 = (const float*)d_in[11]; const float* bf2 = (const float*)d_in[12];
    const float* gamma = (const float*)d_in[13]; const float* beta = (const float*)d_in[14];
    float* out = (float*)d_out;

    const int n  = in_sizes[2];          // 50000
    const int E  = in_sizes[1] / 2;      // 600000
    const int ng = out_size / 64;        // 1000
    const int NB = (n + 1023) / 1024;    // scan blocks (49)

    const int* rows = eidx;              // edge_index[0] (sources)
    const int* cols = eidx + E;          // edge_index[1] (targets)

    // -------- workspace carve (zeroed region first, single memset) --------
    size_t off = 0;
    auto carve = [&](size_t bytes) {
        void* p = (char*)d_ws + off;
        off += (bytes + 511) & ~(size_t)511;
        return p;
    };
    int*   counts = (int*)  carve((size_t)n * 4);        // | zeroed
    int*   cursor = (int*)  carve((size_t)n * 4);        // | zeroed
    int*   gcnt   = (int*)  carve((size_t)(ng + 1) * 4); // | zeroed
    size_t zbytes = off;
    int*   offs   = (int*)  carve((size_t)(n + 1) * 4);
    int*   bsum   = (int*)  carve((size_t)(NB + 1) * 4);
    float* dinv   = (float*)carve((size_t)n * 4);
    int*   esrc   = (int*)  carve((size_t)E * 4);
    int*   goff   = (int*)  carve((size_t)(ng + 1) * 4);
    float* bufA   = (float*)carve((size_t)n * 64 * 4);   // h1' / q
    float* bufB   = (float*)carve((size_t)n * 64 * 4);   // a0(37) / t1 / h3
    (void)ws_size;

    hipMemsetAsync(d_ws, 0, zbytes, stream);

    // -------- CSR build + graph ranges + dinv --------
    int gH = (E + n + 255) / 256;
    hist_kernel<<<gH, 256, 0, stream>>>(cols, counts, E, batch, gcnt, n);
    scan1_kernel<<<NB, 1024, 0, stream>>>(counts, offs, bsum, n);
    scan_meta_kernel<<<1, 1024, 0, stream>>>(bsum, NB, gcnt, goff, ng, n);
    scan3_kernel<<<(n + 255) / 256, 256, 0, stream>>>(offs, bsum, counts, dinv, n, E);
    fill_kernel<<<(E + 255) / 256, 256, 0, stream>>>(rows, cols, offs, cursor, esrc, E);

    // -------- layers --------
    int gagg = (n + 3) / 4;
    // L1: a0 = dinv.*S(dinv.*x)  [gather x directly, per-src weight]
    agg_kernel<37, 1><<<gagg, 256, 0, stream>>>(x, offs, esrc, dinv, nullptr, 0, bufB, n);
    //     h1' = relu(a0@W1+b1).*dinv   (pre-scaled for L2)
    mm_kernel<37, 64><<<(n + 31) / 32, 256, 0, stream>>>(bufB, W1, b1, dinv, 1, bufA, n);
    // L2: t1 = dinv.*S(h1')
    agg_kernel<64, 0><<<gagg, 256, 0, stream>>>(bufA, offs, esrc, dinv, nullptr, 0, bufB, n);
    //     q = (relu(t1@W2+b2))@W3 .* dinv     [fused mm2+mm3]
    mm23_kernel<<<(n + 31) / 32, 256, 0, stream>>>(bufB, W2, b2, W3, dinv, bufA, n);
    // L3: h3 = relu(dinv.*S(q)+b3)
    agg_kernel<64, 0><<<gagg, 256, 0, stream>>>(bufA, offs, esrc, dinv, b3, 1, bufB, n);

    // -------- pool + MLP + LayerNorm --------
    poolmlp_kernel<<<ng, 128, 0, stream>>>(bufB, goff, Wf1, bf1, Wf2, bf2, gamma, beta, out);
}